// Round 1
// baseline (8471.571 us; speedup 1.0000x reference)
//
#include <hip/hip_runtime.h>

#define NN 200000
#define NE 3200000

__device__ __forceinline__ void fadd(float* p, float v) {
  unsafeAtomicAdd(p, v);   // global_atomic_add_f32, not CAS loop
}

// ---------------- conv0: [N,8] -> [N,16] scatter ----------------
__global__ __launch_bounds__(256) void conv0_kernel(
    const float* __restrict__ x, const int* __restrict__ src,
    const int* __restrict__ dst, const float* __restrict__ kw,
    float* __restrict__ h0) {
  int e = blockIdx.x * 256 + threadIdx.x;
  if (e >= NE) return;
  int s = src[e], t = dst[e];
  float k0 = kw[e], k1 = kw[NE + e];
  const float4* xp = reinterpret_cast<const float4*>(x + (size_t)s * 8);
  float4 a = xp[0], b = xp[1];
  float* o = h0 + (size_t)t * 16;
  fadd(o + 0, k0 * a.x); fadd(o + 1, k0 * a.y);
  fadd(o + 2, k0 * a.z); fadd(o + 3, k0 * a.w);
  fadd(o + 4, k0 * b.x); fadd(o + 5, k0 * b.y);
  fadd(o + 6, k0 * b.z); fadd(o + 7, k0 * b.w);
  fadd(o + 8, k1 * a.x); fadd(o + 9, k1 * a.y);
  fadd(o + 10, k1 * a.z); fadd(o + 11, k1 * a.w);
  fadd(o + 12, k1 * b.x); fadd(o + 13, k1 * b.y);
  fadd(o + 14, k1 * b.z); fadd(o + 15, k1 * b.w);
}

// ---------------- mlp0: h0[N,16] @ W0[16,32] + b0, l2norm -> h1[N,32] ----------------
__global__ __launch_bounds__(256) void mlp0_kernel(
    const float* __restrict__ h0, const float* __restrict__ W0,
    const float* __restrict__ b0, float* __restrict__ h1) {
  __shared__ float w0t[32][16];  // w0t[j][k] = W0[k*32+j]
  __shared__ float b0s[32];
  int tid = threadIdx.x;
  for (int i = tid; i < 16 * 32; i += 256) {
    int k = i >> 5, j = i & 31;
    w0t[j][k] = W0[i];
  }
  if (tid < 32) b0s[tid] = b0[tid];
  __syncthreads();
  int node = blockIdx.x * 256 + tid;
  if (node >= NN) return;
  const float4* hp = reinterpret_cast<const float4*>(h0 + (size_t)node * 16);
  float4 h0v = hp[0], h1v = hp[1], h2v = hp[2], h3v = hp[3];
  float o[32];
  float ss = 0.f;
#pragma unroll
  for (int j = 0; j < 32; ++j) {
    const float4* wj = reinterpret_cast<const float4*>(&w0t[j][0]);
    float4 w0v = wj[0], w1v = wj[1], w2v = wj[2], w3v = wj[3];
    float acc = b0s[j];
    acc += h0v.x * w0v.x + h0v.y * w0v.y + h0v.z * w0v.z + h0v.w * w0v.w;
    acc += h1v.x * w1v.x + h1v.y * w1v.y + h1v.z * w1v.z + h1v.w * w1v.w;
    acc += h2v.x * w2v.x + h2v.y * w2v.y + h2v.z * w2v.z + h2v.w * w2v.w;
    acc += h3v.x * w3v.x + h3v.y * w3v.y + h3v.z * w3v.z + h3v.w * w3v.w;
    o[j] = acc;
    ss += acc * acc;
  }
  float inv = 1.f / fmaxf(sqrtf(ss), 1e-12f);
  float4* op = reinterpret_cast<float4*>(h1 + (size_t)node * 32);
#pragma unroll
  for (int j4 = 0; j4 < 8; ++j4) {
    float4 v;
    v.x = o[j4 * 4 + 0] * inv; v.y = o[j4 * 4 + 1] * inv;
    v.z = o[j4 * 4 + 2] * inv; v.w = o[j4 * 4 + 3] * inv;
    op[j4] = v;
  }
}

// ---------------- conv1: h1[N,32] -> g[N,64] scatter (4 threads/edge) ----------------
__global__ __launch_bounds__(256) void conv1_kernel(
    const float* __restrict__ h1, const int* __restrict__ src,
    const int* __restrict__ dst, const float* __restrict__ kw,
    float* __restrict__ g) {
  int idx = blockIdx.x * 256 + threadIdx.x;
  int e = idx >> 2;
  if (e >= NE) return;
  int q = idx & 3;
  int s = src[e], t = dst[e];
  float k0 = kw[e], k1 = kw[NE + e];
  const float4* hp = reinterpret_cast<const float4*>(h1 + (size_t)s * 32 + q * 8);
  float4 a = hp[0], b = hp[1];
  float* o0 = g + (size_t)t * 64 + q * 8;
  float* o1 = o0 + 32;
  fadd(o0 + 0, k0 * a.x); fadd(o0 + 1, k0 * a.y);
  fadd(o0 + 2, k0 * a.z); fadd(o0 + 3, k0 * a.w);
  fadd(o0 + 4, k0 * b.x); fadd(o0 + 5, k0 * b.y);
  fadd(o0 + 6, k0 * b.z); fadd(o0 + 7, k0 * b.w);
  fadd(o1 + 0, k1 * a.x); fadd(o1 + 1, k1 * a.y);
  fadd(o1 + 2, k1 * a.z); fadd(o1 + 3, k1 * a.w);
  fadd(o1 + 4, k1 * b.x); fadd(o1 + 5, k1 * b.y);
  fadd(o1 + 6, k1 * b.z); fadd(o1 + 7, k1 * b.w);
}

// ---------------- mlp1: g[N,64] @ W1[64,128] +b1, relu, @ W2[128,64] +b2, l2norm ----------------
__global__ __launch_bounds__(256) void mlp1_kernel(
    const float* __restrict__ g, const float* __restrict__ W1,
    const float* __restrict__ b1, const float* __restrict__ W2,
    const float* __restrict__ b2, float* __restrict__ out) {
  __shared__ float w1t[128][64];  // w1t[j][k] = W1[k*128+j]
  __shared__ float w2s[128][64];  // w2s[j][c] = W2[j*64+c]
  __shared__ float b1s[128];
  __shared__ float b2s[64];
  int tid = threadIdx.x;
  for (int i = tid; i < 64 * 128; i += 256) {
    int k = i >> 7, j = i & 127;
    w1t[j][k] = W1[i];
    w2s[i >> 6][i & 63] = W2[i];
  }
  if (tid < 128) b1s[tid] = b1[tid];
  if (tid < 64) b2s[tid] = b2[tid];
  __syncthreads();
  int node = blockIdx.x * 256 + tid;
  if (node >= NN) return;

  float gg[64];
  const float4* gp = reinterpret_cast<const float4*>(g + (size_t)node * 64);
#pragma unroll
  for (int k4 = 0; k4 < 16; ++k4) {
    float4 v = gp[k4];
    gg[k4 * 4 + 0] = v.x; gg[k4 * 4 + 1] = v.y;
    gg[k4 * 4 + 2] = v.z; gg[k4 * 4 + 3] = v.w;
  }
  float acc[64];
#pragma unroll
  for (int c = 0; c < 64; ++c) acc[c] = b2s[c];

  for (int j = 0; j < 128; ++j) {
    float hj = b1s[j];
#pragma unroll
    for (int k4 = 0; k4 < 16; ++k4) {
      float4 wv = *reinterpret_cast<const float4*>(&w1t[j][k4 * 4]);
      hj += gg[k4 * 4 + 0] * wv.x + gg[k4 * 4 + 1] * wv.y +
            gg[k4 * 4 + 2] * wv.z + gg[k4 * 4 + 3] * wv.w;
    }
    hj = fmaxf(hj, 0.f);
#pragma unroll
    for (int c4 = 0; c4 < 16; ++c4) {
      float4 wv = *reinterpret_cast<const float4*>(&w2s[j][c4 * 4]);
      acc[c4 * 4 + 0] += hj * wv.x; acc[c4 * 4 + 1] += hj * wv.y;
      acc[c4 * 4 + 2] += hj * wv.z; acc[c4 * 4 + 3] += hj * wv.w;
    }
  }
  float ss = 0.f;
#pragma unroll
  for (int c = 0; c < 64; ++c) ss += acc[c] * acc[c];
  float inv = 1.f / fmaxf(sqrtf(ss), 1e-12f);
  float4* op = reinterpret_cast<float4*>(out + (size_t)node * 64);
#pragma unroll
  for (int c4 = 0; c4 < 16; ++c4) {
    float4 v;
    v.x = acc[c4 * 4 + 0] * inv; v.y = acc[c4 * 4 + 1] * inv;
    v.z = acc[c4 * 4 + 2] * inv; v.w = acc[c4 * 4 + 3] * inv;
    op[c4] = v;
  }
}

extern "C" void kernel_launch(void* const* d_in, const int* in_sizes, int n_in,
                              void* d_out, int out_size, void* d_ws, size_t ws_size,
                              hipStream_t stream) {
  const float* x  = (const float*)d_in[0];
  const int* ei   = (const int*)d_in[1];
  const float* kw = (const float*)d_in[2];
  const float* W0 = (const float*)d_in[3];
  const float* b0 = (const float*)d_in[4];
  const float* W1 = (const float*)d_in[5];
  const float* b1 = (const float*)d_in[6];
  const float* W2 = (const float*)d_in[7];
  const float* b2 = (const float*)d_in[8];
  float* out = (float*)d_out;

  const int* src = ei;
  const int* dst = ei + NE;

  // workspace layout: h1 [N*32] at 0; h0/g share region at +25.6MB (g = N*64)
  float* h1 = (float*)d_ws;
  float* h0 = (float*)((char*)d_ws + (size_t)NN * 32 * 4);
  float* g  = h0;

  // conv0 accumulate
  hipMemsetAsync(h0, 0, (size_t)NN * 16 * 4, stream);
  conv0_kernel<<<(NE + 255) / 256, 256, 0, stream>>>(x, src, dst, kw, h0);
  mlp0_kernel<<<(NN + 255) / 256, 256, 0, stream>>>(h0, W0, b0, h1);

  // conv1 accumulate
  hipMemsetAsync(g, 0, (size_t)NN * 64 * 4, stream);
  conv1_kernel<<<(4 * NE + 255) / 256, 256, 0, stream>>>(h1, src, dst, kw, g);
  mlp1_kernel<<<(NN + 255) / 256, 256, 0, stream>>>(g, W1, b1, W2, b2, out);
}

// Round 2
// 877.039 us; speedup vs baseline: 9.6593x; 9.6593x over previous
//
#include <hip/hip_runtime.h>

#define NN 200000
#define NE 3200000
#define NB_SCAN 782   // ceil(NN/256)

// ======================= CSR build =======================

__global__ __launch_bounds__(256) void hist_kernel(const int* __restrict__ dst,
                                                   int* __restrict__ cnt) {
  int e = blockIdx.x * 256 + threadIdx.x;
  if (e < NE) atomicAdd(&cnt[dst[e]], 1);
}

// per-block inclusive scan of cnt -> offs (within-block inclusive), block sums -> bsums
__global__ __launch_bounds__(256) void scan1_kernel(const int* __restrict__ cnt,
                                                    int* __restrict__ offs,
                                                    int* __restrict__ bsums) {
  __shared__ int s[256];
  int i = blockIdx.x * 256 + threadIdx.x;
  int v = (i < NN) ? cnt[i] : 0;
  s[threadIdx.x] = v;
  __syncthreads();
#pragma unroll
  for (int off = 1; off < 256; off <<= 1) {
    int t = (threadIdx.x >= off) ? s[threadIdx.x - off] : 0;
    __syncthreads();
    s[threadIdx.x] += t;
    __syncthreads();
  }
  if (i < NN) offs[i] = s[threadIdx.x];
  if (threadIdx.x == 255) bsums[blockIdx.x] = s[255];
}

// single-block exclusive scan of bsums[nb] (nb <= 1024)
__global__ __launch_bounds__(1024) void scan2_kernel(int* __restrict__ bsums, int nb) {
  __shared__ int s[1024];
  int v = (threadIdx.x < nb) ? bsums[threadIdx.x] : 0;
  s[threadIdx.x] = v;
  __syncthreads();
#pragma unroll
  for (int off = 1; off < 1024; off <<= 1) {
    int t = (threadIdx.x >= off) ? s[threadIdx.x - off] : 0;
    __syncthreads();
    s[threadIdx.x] += t;
    __syncthreads();
  }
  if (threadIdx.x < nb) bsums[threadIdx.x] = s[threadIdx.x] - v;  // exclusive
}

// offs[i] := exclusive global offset; cursor[i] := same
__global__ __launch_bounds__(256) void scan3_kernel(const int* __restrict__ cnt,
                                                    const int* __restrict__ bsums,
                                                    int* __restrict__ offs,
                                                    int* __restrict__ cursor) {
  int i = blockIdx.x * 256 + threadIdx.x;
  if (i >= NN) return;
  int start = offs[i] - cnt[i] + bsums[blockIdx.x];
  offs[i] = start;
  cursor[i] = start;
}

__global__ __launch_bounds__(256) void scatter_kernel(
    const int* __restrict__ src, const int* __restrict__ dst,
    const float* __restrict__ kw, int* __restrict__ cursor,
    int* __restrict__ ssrc, float* __restrict__ sk0, float* __restrict__ sk1) {
  int e = blockIdx.x * 256 + threadIdx.x;
  if (e >= NE) return;
  int t = dst[e];
  int p = atomicAdd(&cursor[t], 1);
  ssrc[p] = src[e];
  sk0[p] = kw[e];
  sk1[p] = kw[NE + e];
}

// ============== fused conv0 + mlp0 + l2norm -> h1 [N,32] ==============

__global__ __launch_bounds__(256) void fused0_kernel(
    const float* __restrict__ x, const int* __restrict__ offs,
    const int* __restrict__ cnt, const int* __restrict__ ssrc,
    const float* __restrict__ sk0, const float* __restrict__ sk1,
    const float* __restrict__ W0, const float* __restrict__ b0,
    float* __restrict__ h1) {
  __shared__ float w0t[32][16];  // w0t[j][k] = W0[k*32+j]
  __shared__ float b0s[32];
  int tid = threadIdx.x;
  for (int i = tid; i < 16 * 32; i += 256) {
    int k = i >> 5, j = i & 31;
    w0t[j][k] = W0[i];
  }
  if (tid < 32) b0s[tid] = b0[tid];
  __syncthreads();
  int node = blockIdx.x * 256 + tid;
  if (node >= NN) return;

  int start = offs[node];
  int deg = cnt[node];
  float h16[16];
#pragma unroll
  for (int k = 0; k < 16; ++k) h16[k] = 0.f;

  for (int i = 0; i < deg; ++i) {
    int s = ssrc[start + i];
    float k0 = sk0[start + i], k1 = sk1[start + i];
    const float4* xp = reinterpret_cast<const float4*>(x + (size_t)s * 8);
    float4 a = xp[0], b = xp[1];
    h16[0] += k0 * a.x; h16[1] += k0 * a.y; h16[2] += k0 * a.z; h16[3] += k0 * a.w;
    h16[4] += k0 * b.x; h16[5] += k0 * b.y; h16[6] += k0 * b.z; h16[7] += k0 * b.w;
    h16[8]  += k1 * a.x; h16[9]  += k1 * a.y; h16[10] += k1 * a.z; h16[11] += k1 * a.w;
    h16[12] += k1 * b.x; h16[13] += k1 * b.y; h16[14] += k1 * b.z; h16[15] += k1 * b.w;
  }

  float o[32];
  float ss = 0.f;
#pragma unroll
  for (int j = 0; j < 32; ++j) {
    float acc = b0s[j];
#pragma unroll
    for (int k = 0; k < 16; ++k) acc += h16[k] * w0t[j][k];
    o[j] = acc;
    ss += acc * acc;
  }
  float inv = 1.f / fmaxf(sqrtf(ss), 1e-12f);
  float4* op = reinterpret_cast<float4*>(h1 + (size_t)node * 32);
#pragma unroll
  for (int j4 = 0; j4 < 8; ++j4) {
    float4 v;
    v.x = o[j4 * 4 + 0] * inv; v.y = o[j4 * 4 + 1] * inv;
    v.z = o[j4 * 4 + 2] * inv; v.w = o[j4 * 4 + 3] * inv;
    op[j4] = v;
  }
}

// ============== fused conv1 + mlp1 + l2norm -> out [N,64] ==============

__global__ __launch_bounds__(256) void fused1_kernel(
    const float* __restrict__ h1, const int* __restrict__ offs,
    const int* __restrict__ cnt, const int* __restrict__ ssrc,
    const float* __restrict__ sk0, const float* __restrict__ sk1,
    const float* __restrict__ W1, const float* __restrict__ b1,
    const float* __restrict__ W2, const float* __restrict__ b2,
    float* __restrict__ out) {
  __shared__ float w1t[128][64];  // w1t[j][k] = W1[k*128+j]
  __shared__ float w2s[128][64];  // w2s[j][c] = W2[j*64+c]
  __shared__ float b1s[128];
  __shared__ float b2s[64];
  int tid = threadIdx.x;
  for (int i = tid; i < 64 * 128; i += 256) {
    int k = i >> 7, j = i & 127;
    w1t[j][k] = W1[i];
    w2s[i >> 6][i & 63] = W2[i];
  }
  if (tid < 128) b1s[tid] = b1[tid];
  if (tid < 64) b2s[tid] = b2[tid];
  __syncthreads();
  int node = blockIdx.x * 256 + tid;
  if (node >= NN) return;

  int start = offs[node];
  int deg = cnt[node];
  float gg[64];
#pragma unroll
  for (int k = 0; k < 64; ++k) gg[k] = 0.f;

  for (int i = 0; i < deg; ++i) {
    int s = ssrc[start + i];
    float k0 = sk0[start + i], k1 = sk1[start + i];
    const float4* hp = reinterpret_cast<const float4*>(h1 + (size_t)s * 32);
#pragma unroll
    for (int q = 0; q < 8; ++q) {
      float4 v = hp[q];
      gg[q * 4 + 0] += k0 * v.x; gg[q * 4 + 1] += k0 * v.y;
      gg[q * 4 + 2] += k0 * v.z; gg[q * 4 + 3] += k0 * v.w;
      gg[32 + q * 4 + 0] += k1 * v.x; gg[32 + q * 4 + 1] += k1 * v.y;
      gg[32 + q * 4 + 2] += k1 * v.z; gg[32 + q * 4 + 3] += k1 * v.w;
    }
  }

  float acc[64];
#pragma unroll
  for (int c = 0; c < 64; ++c) acc[c] = b2s[c];

  for (int j = 0; j < 128; ++j) {
    float hj = b1s[j];
#pragma unroll
    for (int k4 = 0; k4 < 16; ++k4) {
      float4 wv = *reinterpret_cast<const float4*>(&w1t[j][k4 * 4]);
      hj += gg[k4 * 4 + 0] * wv.x + gg[k4 * 4 + 1] * wv.y +
            gg[k4 * 4 + 2] * wv.z + gg[k4 * 4 + 3] * wv.w;
    }
    hj = fmaxf(hj, 0.f);
#pragma unroll
    for (int c4 = 0; c4 < 16; ++c4) {
      float4 wv = *reinterpret_cast<const float4*>(&w2s[j][c4 * 4]);
      acc[c4 * 4 + 0] += hj * wv.x; acc[c4 * 4 + 1] += hj * wv.y;
      acc[c4 * 4 + 2] += hj * wv.z; acc[c4 * 4 + 3] += hj * wv.w;
    }
  }
  float ss = 0.f;
#pragma unroll
  for (int c = 0; c < 64; ++c) ss += acc[c] * acc[c];
  float inv = 1.f / fmaxf(sqrtf(ss), 1e-12f);
  float4* op = reinterpret_cast<float4*>(out + (size_t)node * 64);
#pragma unroll
  for (int c4 = 0; c4 < 16; ++c4) {
    float4 v;
    v.x = acc[c4 * 4 + 0] * inv; v.y = acc[c4 * 4 + 1] * inv;
    v.z = acc[c4 * 4 + 2] * inv; v.w = acc[c4 * 4 + 3] * inv;
    op[c4] = v;
  }
}

// ======================= launch =======================

extern "C" void kernel_launch(void* const* d_in, const int* in_sizes, int n_in,
                              void* d_out, int out_size, void* d_ws, size_t ws_size,
                              hipStream_t stream) {
  const float* x  = (const float*)d_in[0];
  const int* ei   = (const int*)d_in[1];
  const float* kw = (const float*)d_in[2];
  const float* W0 = (const float*)d_in[3];
  const float* b0 = (const float*)d_in[4];
  const float* W1 = (const float*)d_in[5];
  const float* b1 = (const float*)d_in[6];
  const float* W2 = (const float*)d_in[7];
  const float* b2 = (const float*)d_in[8];
  float* out = (float*)d_out;

  const int* src = ei;
  const int* dst = ei + NE;

  // ws layout (bytes)
  char* p = (char*)d_ws;
  int*   cnt    = (int*)p;                 p += (size_t)NN * 4;      // 0.8 MB
  int*   offs   = (int*)p;                 p += (size_t)NN * 4;      // 0.8 MB
  int*   cursor = (int*)p;                 p += (size_t)NN * 4;      // 0.8 MB
  int*   bsums  = (int*)p;                 p += 1024 * 4;            // 4 KB
  int*   ssrc   = (int*)p;                 p += (size_t)NE * 4;      // 12.8 MB
  float* sk0    = (float*)p;               p += (size_t)NE * 4;      // 12.8 MB
  float* sk1    = (float*)p;               p += (size_t)NE * 4;      // 12.8 MB
  float* h1     = (float*)p;               /* NN*32*4 = 25.6 MB */
  // total ~66.4 MB

  hipMemsetAsync(cnt, 0, (size_t)NN * 4, stream);
  hist_kernel<<<(NE + 255) / 256, 256, 0, stream>>>(dst, cnt);
  scan1_kernel<<<NB_SCAN, 256, 0, stream>>>(cnt, offs, bsums);
  scan2_kernel<<<1, 1024, 0, stream>>>(bsums, NB_SCAN);
  scan3_kernel<<<NB_SCAN, 256, 0, stream>>>(cnt, bsums, offs, cursor);
  scatter_kernel<<<(NE + 255) / 256, 256, 0, stream>>>(src, dst, kw, cursor,
                                                       ssrc, sk0, sk1);

  fused0_kernel<<<NB_SCAN, 256, 0, stream>>>(x, offs, cnt, ssrc, sk0, sk1,
                                             W0, b0, h1);
  fused1_kernel<<<NB_SCAN, 256, 0, stream>>>(h1, offs, cnt, ssrc, sk0, sk1,
                                             W1, b1, W2, b2, out);
}

// Round 3
// 635.311 us; speedup vs baseline: 13.3345x; 1.3805x over previous
//
#include <hip/hip_runtime.h>

#define NN 200000
#define NE 3200000
#define NB_SCAN 782    // ceil(NN/256)
#define NT_MLP1 12500  // NN/16 wave-tiles

using bf16x8 = __attribute__((ext_vector_type(8))) short;
using f32x4  = __attribute__((ext_vector_type(4))) float;

__device__ __forceinline__ float bflo(unsigned u) { return __uint_as_float(u << 16); }
__device__ __forceinline__ float bfhi(unsigned u) { return __uint_as_float(u & 0xffff0000u); }
__device__ __forceinline__ unsigned short f2bfu(float f) {
  unsigned u = __float_as_uint(f);
  return (unsigned short)((u + 0x7fffu + ((u >> 16) & 1u)) >> 16);  // RNE
}
__device__ __forceinline__ unsigned pack2(float a, float b) {
  return (unsigned)f2bfu(a) | ((unsigned)f2bfu(b) << 16);
}

// ======================= CSR build =======================

__global__ __launch_bounds__(256) void hist_kernel(const int* __restrict__ dst,
                                                   int* __restrict__ cnt) {
  int e = blockIdx.x * 256 + threadIdx.x;
  if (e < NE) atomicAdd(&cnt[dst[e]], 1);
}

__global__ __launch_bounds__(256) void scan1_kernel(const int* __restrict__ cnt,
                                                    int* __restrict__ offs,
                                                    int* __restrict__ bsums) {
  __shared__ int s[256];
  int i = blockIdx.x * 256 + threadIdx.x;
  int v = (i < NN) ? cnt[i] : 0;
  s[threadIdx.x] = v;
  __syncthreads();
#pragma unroll
  for (int off = 1; off < 256; off <<= 1) {
    int t = (threadIdx.x >= off) ? s[threadIdx.x - off] : 0;
    __syncthreads();
    s[threadIdx.x] += t;
    __syncthreads();
  }
  if (i < NN) offs[i] = s[threadIdx.x];
  if (threadIdx.x == 255) bsums[blockIdx.x] = s[255];
}

__global__ __launch_bounds__(1024) void scan2_kernel(int* __restrict__ bsums, int nb) {
  __shared__ int s[1024];
  int v = (threadIdx.x < nb) ? bsums[threadIdx.x] : 0;
  s[threadIdx.x] = v;
  __syncthreads();
#pragma unroll
  for (int off = 1; off < 1024; off <<= 1) {
    int t = (threadIdx.x >= off) ? s[threadIdx.x - off] : 0;
    __syncthreads();
    s[threadIdx.x] += t;
    __syncthreads();
  }
  if (threadIdx.x < nb) bsums[threadIdx.x] = s[threadIdx.x] - v;  // exclusive
}

__global__ __launch_bounds__(256) void scan3_kernel(const int* __restrict__ cnt,
                                                    const int* __restrict__ bsums,
                                                    int* __restrict__ offs,
                                                    int* __restrict__ cursor) {
  int i = blockIdx.x * 256 + threadIdx.x;
  if (i >= NN) return;
  int start = offs[i] - cnt[i] + bsums[blockIdx.x];
  offs[i] = start;
  cursor[i] = start;
}

__global__ __launch_bounds__(256) void scatter_kernel(
    const int* __restrict__ src, const int* __restrict__ dst,
    const float* __restrict__ kw, int* __restrict__ cursor,
    int* __restrict__ ssrc, unsigned* __restrict__ skw) {
  int e = blockIdx.x * 256 + threadIdx.x;
  if (e >= NE) return;
  int t = dst[e];
  int p = atomicAdd(&cursor[t], 1);
  ssrc[p] = src[e];
  skw[p] = pack2(kw[e], kw[NE + e]);
}

// ============== fused conv0 + mlp0 + l2norm -> h1 bf16 [N,32] ==============

__global__ __launch_bounds__(256) void fused0_kernel(
    const float* __restrict__ x, const int* __restrict__ offs,
    const int* __restrict__ cnt, const int* __restrict__ ssrc,
    const unsigned* __restrict__ skw,
    const float* __restrict__ W0, const float* __restrict__ b0,
    unsigned short* __restrict__ h1bf) {
  __shared__ float w0t[32][16];  // w0t[j][k] = W0[k*32+j]
  __shared__ float b0s[32];
  int tid = threadIdx.x;
  for (int i = tid; i < 16 * 32; i += 256) {
    int k = i >> 5, j = i & 31;
    w0t[j][k] = W0[i];
  }
  if (tid < 32) b0s[tid] = b0[tid];
  __syncthreads();
  int node = blockIdx.x * 256 + tid;
  if (node >= NN) return;

  int start = offs[node];
  int deg = cnt[node];
  float h16[16];
#pragma unroll
  for (int k = 0; k < 16; ++k) h16[k] = 0.f;

  for (int i = 0; i < deg; ++i) {
    int s = ssrc[start + i];
    unsigned kk = skw[start + i];
    float k0 = bflo(kk), k1 = bfhi(kk);
    const float4* xp = reinterpret_cast<const float4*>(x + (size_t)s * 8);
    float4 a = xp[0], b = xp[1];
    h16[0] += k0 * a.x; h16[1] += k0 * a.y; h16[2] += k0 * a.z; h16[3] += k0 * a.w;
    h16[4] += k0 * b.x; h16[5] += k0 * b.y; h16[6] += k0 * b.z; h16[7] += k0 * b.w;
    h16[8]  += k1 * a.x; h16[9]  += k1 * a.y; h16[10] += k1 * a.z; h16[11] += k1 * a.w;
    h16[12] += k1 * b.x; h16[13] += k1 * b.y; h16[14] += k1 * b.z; h16[15] += k1 * b.w;
  }

  float o[32];
  float ss = 0.f;
#pragma unroll
  for (int j = 0; j < 32; ++j) {
    float acc = b0s[j];
#pragma unroll
    for (int k = 0; k < 16; ++k) acc += h16[k] * w0t[j][k];
    o[j] = acc;
    ss += acc * acc;
  }
  float inv = 1.f / fmaxf(sqrtf(ss), 1e-12f);
  uint4* op = reinterpret_cast<uint4*>(h1bf + (size_t)node * 32);
#pragma unroll
  for (int c = 0; c < 4; ++c) {
    uint4 u;
    u.x = pack2(o[c * 8 + 0] * inv, o[c * 8 + 1] * inv);
    u.y = pack2(o[c * 8 + 2] * inv, o[c * 8 + 3] * inv);
    u.z = pack2(o[c * 8 + 4] * inv, o[c * 8 + 5] * inv);
    u.w = pack2(o[c * 8 + 6] * inv, o[c * 8 + 7] * inv);
    op[c] = u;
  }
}

// ============== gather1: CSR gather of h1 -> g bf16 [N,64] (no LDS) ==============

__global__ __launch_bounds__(256) void gather1_kernel(
    const unsigned short* __restrict__ h1bf, const int* __restrict__ offs,
    const int* __restrict__ cnt, const int* __restrict__ ssrc,
    const unsigned* __restrict__ skw, unsigned short* __restrict__ gbf) {
  int node = blockIdx.x * 256 + threadIdx.x;
  if (node >= NN) return;
  int start = offs[node];
  int deg = cnt[node];
  float gg[64];
#pragma unroll
  for (int k = 0; k < 64; ++k) gg[k] = 0.f;

  for (int i = 0; i < deg; ++i) {
    int s = ssrc[start + i];
    unsigned kk = skw[start + i];
    float k0 = bflo(kk), k1 = bfhi(kk);
    const uint4* hp = reinterpret_cast<const uint4*>(h1bf + (size_t)s * 32);
#pragma unroll
    for (int c = 0; c < 4; ++c) {
      uint4 u = hp[c];
      float v0 = bflo(u.x), v1 = bfhi(u.x);
      float v2 = bflo(u.y), v3 = bfhi(u.y);
      float v4 = bflo(u.z), v5 = bfhi(u.z);
      float v6 = bflo(u.w), v7 = bfhi(u.w);
      int j = c * 8;
      gg[j + 0] += k0 * v0; gg[j + 1] += k0 * v1;
      gg[j + 2] += k0 * v2; gg[j + 3] += k0 * v3;
      gg[j + 4] += k0 * v4; gg[j + 5] += k0 * v5;
      gg[j + 6] += k0 * v6; gg[j + 7] += k0 * v7;
      gg[32 + j + 0] += k1 * v0; gg[32 + j + 1] += k1 * v1;
      gg[32 + j + 2] += k1 * v2; gg[32 + j + 3] += k1 * v3;
      gg[32 + j + 4] += k1 * v4; gg[32 + j + 5] += k1 * v5;
      gg[32 + j + 6] += k1 * v6; gg[32 + j + 7] += k1 * v7;
    }
  }

  uint4* go = reinterpret_cast<uint4*>(gbf + (size_t)node * 64);
#pragma unroll
  for (int c = 0; c < 8; ++c) {
    uint4 u;
    u.x = pack2(gg[c * 8 + 0], gg[c * 8 + 1]);
    u.y = pack2(gg[c * 8 + 2], gg[c * 8 + 3]);
    u.z = pack2(gg[c * 8 + 4], gg[c * 8 + 5]);
    u.w = pack2(gg[c * 8 + 6], gg[c * 8 + 7]);
    go[c] = u;
  }
}

// ============== mlp1: g[N,64]bf16 @ W1 -> relu -> @ W2 -> l2norm -> out f32 ==============
// MFMA 16x16x32_bf16. Per wave-tile: 16 nodes.
// A layout: row=lane&15, k=(lane>>4)*8+i ; B: col=lane&15, k=(lane>>4)*8+i
// D layout: col=lane&15, row=(lane>>4)*4+q   [m89-verified]

__global__ __launch_bounds__(256) void mlp1_kernel(
    const unsigned short* __restrict__ gbf,
    const float* __restrict__ W1, const float* __restrict__ b1,
    const float* __restrict__ W2, const float* __restrict__ b2,
    float* __restrict__ out) {
  __shared__ __align__(16) short hlds[4][16][136];  // per-wave h transpose, 17.4 KB
  int tid = threadIdx.x;
  int wave = tid >> 6, lane = tid & 63;
  int lg = lane >> 4;   // lane group 0..3
  int lr = lane & 15;   // 0..15

  // --- weights -> register fragments (once per block) ---
  bf16x8 w1f[8][2];     // n-tile (128 cols / 16), k-step (64 / 32)
#pragma unroll
  for (int n = 0; n < 8; ++n)
#pragma unroll
    for (int ks = 0; ks < 2; ++ks) {
      bf16x8 f;
#pragma unroll
      for (int i = 0; i < 8; ++i)
        f[i] = (short)f2bfu(W1[(size_t)(ks * 32 + lg * 8 + i) * 128 + n * 16 + lr]);
      w1f[n][ks] = f;
    }
  bf16x8 w2f[4][4];     // n2-tile (64 cols / 16), k-step (128 / 32)
#pragma unroll
  for (int n2 = 0; n2 < 4; ++n2)
#pragma unroll
    for (int ks = 0; ks < 4; ++ks) {
      bf16x8 f;
#pragma unroll
      for (int i = 0; i < 8; ++i)
        f[i] = (short)f2bfu(W2[(size_t)(ks * 32 + lg * 8 + i) * 64 + n2 * 16 + lr]);
      w2f[n2][ks] = f;
    }
  float b1v[8], b2v[4];
#pragma unroll
  for (int n = 0; n < 8; ++n) b1v[n] = b1[n * 16 + lr];
#pragma unroll
  for (int n2 = 0; n2 < 4; ++n2) b2v[n2] = b2[n2 * 16 + lr];

  for (int tile = blockIdx.x * 4 + wave; tile < NT_MLP1; tile += gridDim.x * 4) {
    int base = tile * 16;
    const bf16x8* grow = reinterpret_cast<const bf16x8*>(gbf + (size_t)(base + lr) * 64);
    bf16x8 a1_0 = grow[lg];      // k = lg*8..+8
    bf16x8 a1_1 = grow[4 + lg];  // k = 32 + lg*8..+8

    // GEMM1 + bias + relu -> hlds (bf16, transposed layout for A2)
#pragma unroll
    for (int n = 0; n < 8; ++n) {
      f32x4 acc = {0.f, 0.f, 0.f, 0.f};
      acc = __builtin_amdgcn_mfma_f32_16x16x32_bf16(a1_0, w1f[n][0], acc, 0, 0, 0);
      acc = __builtin_amdgcn_mfma_f32_16x16x32_bf16(a1_1, w1f[n][1], acc, 0, 0, 0);
#pragma unroll
      for (int q = 0; q < 4; ++q) {
        float v = fmaxf(acc[q] + b1v[n], 0.f);
        hlds[wave][lg * 4 + q][n * 16 + lr] = (short)f2bfu(v);
      }
    }

    // GEMM2
    bf16x8 a2[4];
#pragma unroll
    for (int ks = 0; ks < 4; ++ks)
      a2[ks] = *reinterpret_cast<const bf16x8*>(&hlds[wave][lr][ks * 32 + lg * 8]);
    f32x4 acc2[4];
#pragma unroll
    for (int n2 = 0; n2 < 4; ++n2) {
      f32x4 a = {0.f, 0.f, 0.f, 0.f};
#pragma unroll
      for (int ks = 0; ks < 4; ++ks)
        a = __builtin_amdgcn_mfma_f32_16x16x32_bf16(a2[ks], w2f[n2][ks], a, 0, 0, 0);
      acc2[n2] = a;
    }

    // bias + l2norm + store
#pragma unroll
    for (int q = 0; q < 4; ++q) {
      float s = 0.f;
#pragma unroll
      for (int n2 = 0; n2 < 4; ++n2) {
        float v = acc2[n2][q] + b2v[n2];
        s += v * v;
      }
      s += __shfl_xor(s, 1); s += __shfl_xor(s, 2);
      s += __shfl_xor(s, 4); s += __shfl_xor(s, 8);
      float inv = 1.f / fmaxf(sqrtf(s), 1e-12f);
      size_t rowoff = (size_t)(base + lg * 4 + q) * 64 + lr;
#pragma unroll
      for (int n2 = 0; n2 < 4; ++n2)
        out[rowoff + n2 * 16] = (acc2[n2][q] + b2v[n2]) * inv;
    }
  }
}

// ======================= launch =======================

extern "C" void kernel_launch(void* const* d_in, const int* in_sizes, int n_in,
                              void* d_out, int out_size, void* d_ws, size_t ws_size,
                              hipStream_t stream) {
  const float* x  = (const float*)d_in[0];
  const int* ei   = (const int*)d_in[1];
  const float* kw = (const float*)d_in[2];
  const float* W0 = (const float*)d_in[3];
  const float* b0 = (const float*)d_in[4];
  const float* W1 = (const float*)d_in[5];
  const float* b1 = (const float*)d_in[6];
  const float* W2 = (const float*)d_in[7];
  const float* b2 = (const float*)d_in[8];
  float* out = (float*)d_out;

  const int* src = ei;
  const int* dst = ei + NE;

  // ws layout (bytes): ~66.4 MB total
  char* p = (char*)d_ws;
  int*      cnt    = (int*)p;        p += (size_t)NN * 4;       // 0.8 MB
  int*      offs   = (int*)p;        p += (size_t)NN * 4;       // 0.8 MB
  int*      cursor = (int*)p;        p += (size_t)NN * 4;       // 0.8 MB
  int*      bsums  = (int*)p;        p += 1024 * 4;             // 4 KB
  int*      ssrc   = (int*)p;        p += (size_t)NE * 4;       // 12.8 MB
  unsigned* skw    = (unsigned*)p;   p += (size_t)NE * 4;       // 12.8 MB
  unsigned short* h1bf = (unsigned short*)p; p += (size_t)NN * 32 * 2;  // 12.8 MB
  unsigned short* gbf  = (unsigned short*)p;                    // 25.6 MB

  hipMemsetAsync(cnt, 0, (size_t)NN * 4, stream);
  hist_kernel<<<(NE + 255) / 256, 256, 0, stream>>>(dst, cnt);
  scan1_kernel<<<NB_SCAN, 256, 0, stream>>>(cnt, offs, bsums);
  scan2_kernel<<<1, 1024, 0, stream>>>(bsums, NB_SCAN);
  scan3_kernel<<<NB_SCAN, 256, 0, stream>>>(cnt, bsums, offs, cursor);
  scatter_kernel<<<(NE + 255) / 256, 256, 0, stream>>>(src, dst, kw, cursor,
                                                       ssrc, skw);

  fused0_kernel<<<NB_SCAN, 256, 0, stream>>>(x, offs, cnt, ssrc, skw, W0, b0, h1bf);
  gather1_kernel<<<NB_SCAN, 256, 0, stream>>>(h1bf, offs, cnt, ssrc, skw, gbf);
  mlp1_kernel<<<768, 256, 0, stream>>>(gbf, W1, b1, W2, b2, out);
}

// Round 4
// 343.935 us; speedup vs baseline: 24.6313x; 1.8472x over previous
//
#include <hip/hip_runtime.h>

#define NN 200000
#define NE 3200000
#define NB_SCAN 782    // ceil(NN/256) node-scan blocks
#define NBUCK 782      // node buckets of 256 nodes (dst>>8)
#define NBLK_A 512     // bucket-pass blocks
#define EPB (NE / NBLK_A)  // 6250 edges per bucket-pass block
#define NT_MLP1 12500  // NN/16 wave-tiles

using bf16x8 = __attribute__((ext_vector_type(8))) short;
using f32x4  = __attribute__((ext_vector_type(4))) float;

__device__ __forceinline__ float bflo(unsigned u) { return __uint_as_float(u << 16); }
__device__ __forceinline__ float bfhi(unsigned u) { return __uint_as_float(u & 0xffff0000u); }
__device__ __forceinline__ unsigned short f2bfu(float f) {
  unsigned u = __float_as_uint(f);
  return (unsigned short)((u + 0x7fffu + ((u >> 16) & 1u)) >> 16);  // RNE
}
__device__ __forceinline__ unsigned pack2(float a, float b) {
  return (unsigned)f2bfu(a) | ((unsigned)f2bfu(b) << 16);
}

// ======================= stage 1: bucket histogram (LDS) =======================

__global__ __launch_bounds__(256) void bhist_kernel(const int* __restrict__ dst,
                                                    int* __restrict__ bhT) {
  __shared__ int h[NBUCK];
  for (int k = threadIdx.x; k < NBUCK; k += 256) h[k] = 0;
  __syncthreads();
  int base = blockIdx.x * EPB;
  for (int i = threadIdx.x; i < EPB; i += 256)
    atomicAdd(&h[dst[base + i] >> 8], 1);
  __syncthreads();
  for (int k = threadIdx.x; k < NBUCK; k += 256)
    bhT[k * NBLK_A + blockIdx.x] = h[k];
}

// per-bucket exclusive scan over the 512 block entries -> bhT in place, totals
__global__ __launch_bounds__(512) void bscan_kernel(int* __restrict__ bhT,
                                                    int* __restrict__ btot) {
  __shared__ int s[512];
  int b = blockIdx.x;
  int v = bhT[b * NBLK_A + threadIdx.x];
  s[threadIdx.x] = v;
  __syncthreads();
#pragma unroll
  for (int off = 1; off < 512; off <<= 1) {
    int t = (threadIdx.x >= off) ? s[threadIdx.x - off] : 0;
    __syncthreads();
    s[threadIdx.x] += t;
    __syncthreads();
  }
  bhT[b * NBLK_A + threadIdx.x] = s[threadIdx.x] - v;  // exclusive
  if (threadIdx.x == 511) btot[b] = s[511];
}

// exclusive scan of btot[NBUCK] -> bbase[NBUCK+1]
__global__ __launch_bounds__(1024) void bbase_kernel(const int* __restrict__ btot,
                                                     int* __restrict__ bbase) {
  __shared__ int s[1024];
  int v = (threadIdx.x < NBUCK) ? btot[threadIdx.x] : 0;
  s[threadIdx.x] = v;
  __syncthreads();
#pragma unroll
  for (int off = 1; off < 1024; off <<= 1) {
    int t = (threadIdx.x >= off) ? s[threadIdx.x - off] : 0;
    __syncthreads();
    s[threadIdx.x] += t;
    __syncthreads();
  }
  if (threadIdx.x < NBUCK) bbase[threadIdx.x] = s[threadIdx.x] - v;
  if (threadIdx.x == NBUCK - 1) bbase[NBUCK] = s[threadIdx.x];
}

// bucket placement: write packed edge {src | dst_lo<<24, kw2} bucket-sorted
__global__ __launch_bounds__(256) void bplace_kernel(
    const int* __restrict__ src, const int* __restrict__ dst,
    const float* __restrict__ kw, const int* __restrict__ bhT,
    const int* __restrict__ bbase, uint2* __restrict__ bsorted) {
  __shared__ int cur[NBUCK];
  for (int k = threadIdx.x; k < NBUCK; k += 256)
    cur[k] = bbase[k] + bhT[k * NBLK_A + blockIdx.x];
  __syncthreads();
  int base = blockIdx.x * EPB;
  for (int i = threadIdx.x; i < EPB; i += 256) {
    int e = base + i;
    int d = dst[e];
    int p = atomicAdd(&cur[d >> 8], 1);
    uint2 u;
    u.x = (unsigned)src[e] | ((unsigned)(d & 255) << 24);
    u.y = pack2(kw[e], kw[NE + e]);
    bsorted[p] = u;
  }
}

// ======================= stage 2: per-node counts (LDS) =======================

__global__ __launch_bounds__(256) void nhist_kernel(const uint2* __restrict__ bsorted,
                                                    const int* __restrict__ bbase,
                                                    int* __restrict__ cnt) {
  __shared__ int h[256];
  h[threadIdx.x] = 0;
  __syncthreads();
  int b = blockIdx.x;
  int r0 = bbase[b], r1 = bbase[b + 1];
  for (int i = r0 + threadIdx.x; i < r1; i += 256)
    atomicAdd(&h[bsorted[i].x >> 24], 1);
  __syncthreads();
  int node = b * 256 + threadIdx.x;
  if (node < NN) cnt[node] = h[threadIdx.x];
}

// node-level scans (global exclusive offsets)
__global__ __launch_bounds__(256) void scan1_kernel(const int* __restrict__ cnt,
                                                    int* __restrict__ offs,
                                                    int* __restrict__ bsums) {
  __shared__ int s[256];
  int i = blockIdx.x * 256 + threadIdx.x;
  int v = (i < NN) ? cnt[i] : 0;
  s[threadIdx.x] = v;
  __syncthreads();
#pragma unroll
  for (int off = 1; off < 256; off <<= 1) {
    int t = (threadIdx.x >= off) ? s[threadIdx.x - off] : 0;
    __syncthreads();
    s[threadIdx.x] += t;
    __syncthreads();
  }
  if (i < NN) offs[i] = s[threadIdx.x];
  if (threadIdx.x == 255) bsums[blockIdx.x] = s[255];
}

__global__ __launch_bounds__(1024) void scan2_kernel(int* __restrict__ bsums, int nb) {
  __shared__ int s[1024];
  int v = (threadIdx.x < nb) ? bsums[threadIdx.x] : 0;
  s[threadIdx.x] = v;
  __syncthreads();
#pragma unroll
  for (int off = 1; off < 1024; off <<= 1) {
    int t = (threadIdx.x >= off) ? s[threadIdx.x - off] : 0;
    __syncthreads();
    s[threadIdx.x] += t;
    __syncthreads();
  }
  if (threadIdx.x < nb) bsums[threadIdx.x] = s[threadIdx.x] - v;  // exclusive
}

__global__ __launch_bounds__(256) void scan3_kernel(const int* __restrict__ cnt,
                                                    const int* __restrict__ bsums,
                                                    int* __restrict__ offs) {
  int i = blockIdx.x * 256 + threadIdx.x;
  if (i >= NN) return;
  offs[i] = offs[i] - cnt[i] + bsums[blockIdx.x];
}

// final placement within bucket window (L2-resident writes)
__global__ __launch_bounds__(256) void nplace_kernel(const uint2* __restrict__ bsorted,
                                                     const int* __restrict__ bbase,
                                                     const int* __restrict__ offs,
                                                     uint2* __restrict__ sedge) {
  __shared__ int cur[256];
  int b = blockIdx.x;
  int node = b * 256 + threadIdx.x;
  cur[threadIdx.x] = (node < NN) ? offs[node] : 0;
  __syncthreads();
  int r0 = bbase[b], r1 = bbase[b + 1];
  for (int i = r0 + threadIdx.x; i < r1; i += 256) {
    uint2 u = bsorted[i];
    int p = atomicAdd(&cur[u.x >> 24], 1);
    u.x &= 0x00FFFFFFu;  // pure src index
    sedge[p] = u;
  }
}

// ============== fused conv0 + mlp0 + l2norm -> h1 bf16 [N,32] ==============

__global__ __launch_bounds__(256) void fused0_kernel(
    const float* __restrict__ x, const int* __restrict__ offs,
    const int* __restrict__ cnt, const uint2* __restrict__ sedge,
    const float* __restrict__ W0, const float* __restrict__ b0,
    unsigned short* __restrict__ h1bf) {
  __shared__ float w0t[32][16];  // w0t[j][k] = W0[k*32+j]
  __shared__ float b0s[32];
  int tid = threadIdx.x;
  for (int i = tid; i < 16 * 32; i += 256) {
    int k = i >> 5, j = i & 31;
    w0t[j][k] = W0[i];
  }
  if (tid < 32) b0s[tid] = b0[tid];
  __syncthreads();
  int node = blockIdx.x * 256 + tid;
  if (node >= NN) return;

  int start = offs[node];
  int deg = cnt[node];
  float h16[16];
#pragma unroll
  for (int k = 0; k < 16; ++k) h16[k] = 0.f;

  for (int i = 0; i < deg; ++i) {
    uint2 e = sedge[start + i];
    float k0 = bflo(e.y), k1 = bfhi(e.y);
    const float4* xp = reinterpret_cast<const float4*>(x + (size_t)e.x * 8);
    float4 a = xp[0], b = xp[1];
    h16[0] += k0 * a.x; h16[1] += k0 * a.y; h16[2] += k0 * a.z; h16[3] += k0 * a.w;
    h16[4] += k0 * b.x; h16[5] += k0 * b.y; h16[6] += k0 * b.z; h16[7] += k0 * b.w;
    h16[8]  += k1 * a.x; h16[9]  += k1 * a.y; h16[10] += k1 * a.z; h16[11] += k1 * a.w;
    h16[12] += k1 * b.x; h16[13] += k1 * b.y; h16[14] += k1 * b.z; h16[15] += k1 * b.w;
  }

  float o[32];
  float ss = 0.f;
#pragma unroll
  for (int j = 0; j < 32; ++j) {
    float acc = b0s[j];
#pragma unroll
    for (int k = 0; k < 16; ++k) acc += h16[k] * w0t[j][k];
    o[j] = acc;
    ss += acc * acc;
  }
  float inv = 1.f / fmaxf(sqrtf(ss), 1e-12f);
  uint4* op = reinterpret_cast<uint4*>(h1bf + (size_t)node * 32);
#pragma unroll
  for (int c = 0; c < 4; ++c) {
    uint4 u;
    u.x = pack2(o[c * 8 + 0] * inv, o[c * 8 + 1] * inv);
    u.y = pack2(o[c * 8 + 2] * inv, o[c * 8 + 3] * inv);
    u.z = pack2(o[c * 8 + 4] * inv, o[c * 8 + 5] * inv);
    u.w = pack2(o[c * 8 + 6] * inv, o[c * 8 + 7] * inv);
    op[c] = u;
  }
}

// ============== gather1: CSR gather of h1 -> g bf16 [N,64] ==============

__global__ __launch_bounds__(256) void gather1_kernel(
    const unsigned short* __restrict__ h1bf, const int* __restrict__ offs,
    const int* __restrict__ cnt, const uint2* __restrict__ sedge,
    unsigned short* __restrict__ gbf) {
  int node = blockIdx.x * 256 + threadIdx.x;
  if (node >= NN) return;
  int start = offs[node];
  int deg = cnt[node];
  float gg[64];
#pragma unroll
  for (int k = 0; k < 64; ++k) gg[k] = 0.f;

  for (int i = 0; i < deg; ++i) {
    uint2 e = sedge[start + i];
    float k0 = bflo(e.y), k1 = bfhi(e.y);
    const uint4* hp = reinterpret_cast<const uint4*>(h1bf + (size_t)e.x * 32);
#pragma unroll
    for (int c = 0; c < 4; ++c) {
      uint4 u = hp[c];
      float v0 = bflo(u.x), v1 = bfhi(u.x);
      float v2 = bflo(u.y), v3 = bfhi(u.y);
      float v4 = bflo(u.z), v5 = bfhi(u.z);
      float v6 = bflo(u.w), v7 = bfhi(u.w);
      int j = c * 8;
      gg[j + 0] += k0 * v0; gg[j + 1] += k0 * v1;
      gg[j + 2] += k0 * v2; gg[j + 3] += k0 * v3;
      gg[j + 4] += k0 * v4; gg[j + 5] += k0 * v5;
      gg[j + 6] += k0 * v6; gg[j + 7] += k0 * v7;
      gg[32 + j + 0] += k1 * v0; gg[32 + j + 1] += k1 * v1;
      gg[32 + j + 2] += k1 * v2; gg[32 + j + 3] += k1 * v3;
      gg[32 + j + 4] += k1 * v4; gg[32 + j + 5] += k1 * v5;
      gg[32 + j + 6] += k1 * v6; gg[32 + j + 7] += k1 * v7;
    }
  }

  uint4* go = reinterpret_cast<uint4*>(gbf + (size_t)node * 64);
#pragma unroll
  for (int c = 0; c < 8; ++c) {
    uint4 u;
    u.x = pack2(gg[c * 8 + 0], gg[c * 8 + 1]);
    u.y = pack2(gg[c * 8 + 2], gg[c * 8 + 3]);
    u.z = pack2(gg[c * 8 + 4], gg[c * 8 + 5]);
    u.w = pack2(gg[c * 8 + 6], gg[c * 8 + 7]);
    go[c] = u;
  }
}

// ============== mlp1: MFMA 16x16x32_bf16, 16 nodes per wave-tile ==============
// A: row=lane&15, k=(lane>>4)*8+i ; B: col=lane&15, k=(lane>>4)*8+i
// D: col=lane&15, row=(lane>>4)*4+q   [m89-verified]

__global__ __launch_bounds__(256) void mlp1_kernel(
    const unsigned short* __restrict__ gbf,
    const float* __restrict__ W1, const float* __restrict__ b1,
    const float* __restrict__ W2, const float* __restrict__ b2,
    float* __restrict__ out) {
  __shared__ __align__(16) short hlds[4][16][136];
  int tid = threadIdx.x;
  int wave = tid >> 6, lane = tid & 63;
  int lg = lane >> 4;
  int lr = lane & 15;

  bf16x8 w1f[8][2];
#pragma unroll
  for (int n = 0; n < 8; ++n)
#pragma unroll
    for (int ks = 0; ks < 2; ++ks) {
      bf16x8 f;
#pragma unroll
      for (int i = 0; i < 8; ++i)
        f[i] = (short)f2bfu(W1[(size_t)(ks * 32 + lg * 8 + i) * 128 + n * 16 + lr]);
      w1f[n][ks] = f;
    }
  bf16x8 w2f[4][4];
#pragma unroll
  for (int n2 = 0; n2 < 4; ++n2)
#pragma unroll
    for (int ks = 0; ks < 4; ++ks) {
      bf16x8 f;
#pragma unroll
      for (int i = 0; i < 8; ++i)
        f[i] = (short)f2bfu(W2[(size_t)(ks * 32 + lg * 8 + i) * 64 + n2 * 16 + lr]);
      w2f[n2][ks] = f;
    }
  float b1v[8], b2v[4];
#pragma unroll
  for (int n = 0; n < 8; ++n) b1v[n] = b1[n * 16 + lr];
#pragma unroll
  for (int n2 = 0; n2 < 4; ++n2) b2v[n2] = b2[n2 * 16 + lr];

  for (int tile = blockIdx.x * 4 + wave; tile < NT_MLP1; tile += gridDim.x * 4) {
    int base = tile * 16;
    const bf16x8* grow = reinterpret_cast<const bf16x8*>(gbf + (size_t)(base + lr) * 64);
    bf16x8 a1_0 = grow[lg];
    bf16x8 a1_1 = grow[4 + lg];

#pragma unroll
    for (int n = 0; n < 8; ++n) {
      f32x4 acc = {0.f, 0.f, 0.f, 0.f};
      acc = __builtin_amdgcn_mfma_f32_16x16x32_bf16(a1_0, w1f[n][0], acc, 0, 0, 0);
      acc = __builtin_amdgcn_mfma_f32_16x16x32_bf16(a1_1, w1f[n][1], acc, 0, 0, 0);
#pragma unroll
      for (int q = 0; q < 4; ++q) {
        float v = fmaxf(acc[q] + b1v[n], 0.f);
        hlds[wave][lg * 4 + q][n * 16 + lr] = (short)f2bfu(v);
      }
    }

    bf16x8 a2[4];
#pragma unroll
    for (int ks = 0; ks < 4; ++ks)
      a2[ks] = *reinterpret_cast<const bf16x8*>(&hlds[wave][lr][ks * 32 + lg * 8]);
    f32x4 acc2[4];
#pragma unroll
    for (int n2 = 0; n2 < 4; ++n2) {
      f32x4 a = {0.f, 0.f, 0.f, 0.f};
#pragma unroll
      for (int ks = 0; ks < 4; ++ks)
        a = __builtin_amdgcn_mfma_f32_16x16x32_bf16(a2[ks], w2f[n2][ks], a, 0, 0, 0);
      acc2[n2] = a;
    }

#pragma unroll
    for (int q = 0; q < 4; ++q) {
      float s = 0.f;
#pragma unroll
      for (int n2 = 0; n2 < 4; ++n2) {
        float v = acc2[n2][q] + b2v[n2];
        s += v * v;
      }
      s += __shfl_xor(s, 1); s += __shfl_xor(s, 2);
      s += __shfl_xor(s, 4); s += __shfl_xor(s, 8);
      float inv = 1.f / fmaxf(sqrtf(s), 1e-12f);
      size_t rowoff = (size_t)(base + lg * 4 + q) * 64 + lr;
#pragma unroll
      for (int n2 = 0; n2 < 4; ++n2)
        out[rowoff + n2 * 16] = (acc2[n2][q] + b2v[n2]) * inv;
    }
  }
}

// ======================= launch =======================

extern "C" void kernel_launch(void* const* d_in, const int* in_sizes, int n_in,
                              void* d_out, int out_size, void* d_ws, size_t ws_size,
                              hipStream_t stream) {
  const float* x  = (const float*)d_in[0];
  const int* ei   = (const int*)d_in[1];
  const float* kw = (const float*)d_in[2];
  const float* W0 = (const float*)d_in[3];
  const float* b0 = (const float*)d_in[4];
  const float* W1 = (const float*)d_in[5];
  const float* b1 = (const float*)d_in[6];
  const float* W2 = (const float*)d_in[7];
  const float* b2 = (const float*)d_in[8];
  float* out = (float*)d_out;

  const int* src = ei;
  const int* dst = ei + NE;

  // ws layout (8B-aligned chunks), ~67 MB total:
  char* p = (char*)d_ws;
  uint2* bsorted = (uint2*)p;              p += (size_t)NE * 8;          // 25.6 MB
  uint2* sedge   = (uint2*)p;              p += (size_t)NE * 8;          // 25.6 MB
  unsigned short* h1bf = (unsigned short*)p; p += (size_t)NN * 32 * 2;   // 12.8 MB
  int* bhT   = (int*)p;                    p += (size_t)NBUCK * NBLK_A * 4;  // 1.6 MB
  int* btot  = (int*)p;                    p += (size_t)NBUCK * 4;
  int* bbase = (int*)p;                    p += (size_t)(NBUCK + 1) * 4;
  int* cnt   = (int*)p;                    p += (size_t)NN * 4;          // 0.8 MB
  int* offs  = (int*)p;                    p += (size_t)NN * 4;          // 0.8 MB
  int* bsums = (int*)p;                    p += 1024 * 4;
  // gbf reuses bsorted (dead after nplace); NN*64*2 == NE*8 bytes exactly.
  unsigned short* gbf = (unsigned short*)bsorted;

  bhist_kernel<<<NBLK_A, 256, 0, stream>>>(dst, bhT);
  bscan_kernel<<<NBUCK, 512, 0, stream>>>(bhT, btot);
  bbase_kernel<<<1, 1024, 0, stream>>>(btot, bbase);
  bplace_kernel<<<NBLK_A, 256, 0, stream>>>(src, dst, kw, bhT, bbase, bsorted);

  nhist_kernel<<<NBUCK, 256, 0, stream>>>(bsorted, bbase, cnt);
  scan1_kernel<<<NB_SCAN, 256, 0, stream>>>(cnt, offs, bsums);
  scan2_kernel<<<1, 1024, 0, stream>>>(bsums, NB_SCAN);
  scan3_kernel<<<NB_SCAN, 256, 0, stream>>>(cnt, bsums, offs);
  nplace_kernel<<<NBUCK, 256, 0, stream>>>(bsorted, bbase, offs, sedge);

  fused0_kernel<<<NB_SCAN, 256, 0, stream>>>(x, offs, cnt, sedge, W0, b0, h1bf);
  gather1_kernel<<<NB_SCAN, 256, 0, stream>>>(h1bf, offs, cnt, sedge, gbf);
  mlp1_kernel<<<768, 256, 0, stream>>>(gbf, W1, b1, W2, b2, out);
}

// Round 5
// 273.410 us; speedup vs baseline: 30.9848x; 1.2579x over previous
//
#include <hip/hip_runtime.h>

#define NN 200000
#define NE 3200000
#define NB_SCAN 782    // ceil(NN/256) node-scan blocks
#define NBUCK 782      // node buckets of 256 nodes (dst>>8)
#define NBLK_A 512     // bucket-pass blocks
#define EPB (NE / NBLK_A)  // 6250 edges per bucket-pass block
#define NT_MLP1 12500  // NN/16 wave-tiles

using bf16x8 = __attribute__((ext_vector_type(8))) short;
using f32x4  = __attribute__((ext_vector_type(4))) float;

__device__ __forceinline__ float bflo(unsigned u) { return __uint_as_float(u << 16); }
__device__ __forceinline__ float bfhi(unsigned u) { return __uint_as_float(u & 0xffff0000u); }
__device__ __forceinline__ unsigned short f2bfu(float f) {
  unsigned u = __float_as_uint(f);
  return (unsigned short)((u + 0x7fffu + ((u >> 16) & 1u)) >> 16);  // RNE
}
__device__ __forceinline__ unsigned pack2(float a, float b) {
  return (unsigned)f2bfu(a) | ((unsigned)f2bfu(b) << 16);
}

// ======================= stage 1: bucket histogram (LDS) =======================

__global__ __launch_bounds__(256) void bhist_kernel(const int* __restrict__ dst,
                                                    int* __restrict__ bhT) {
  __shared__ int h[NBUCK];
  for (int k = threadIdx.x; k < NBUCK; k += 256) h[k] = 0;
  __syncthreads();
  int base = blockIdx.x * EPB;
  for (int i = threadIdx.x; i < EPB; i += 256)
    atomicAdd(&h[dst[base + i] >> 8], 1);
  __syncthreads();
  for (int k = threadIdx.x; k < NBUCK; k += 256)
    bhT[k * NBLK_A + blockIdx.x] = h[k];
}

// per-bucket exclusive scan over the 512 block entries -> bhT in place, totals
__global__ __launch_bounds__(512) void bscan_kernel(int* __restrict__ bhT,
                                                    int* __restrict__ btot) {
  __shared__ int s[512];
  int b = blockIdx.x;
  int v = bhT[b * NBLK_A + threadIdx.x];
  s[threadIdx.x] = v;
  __syncthreads();
#pragma unroll
  for (int off = 1; off < 512; off <<= 1) {
    int t = (threadIdx.x >= off) ? s[threadIdx.x - off] : 0;
    __syncthreads();
    s[threadIdx.x] += t;
    __syncthreads();
  }
  bhT[b * NBLK_A + threadIdx.x] = s[threadIdx.x] - v;  // exclusive
  if (threadIdx.x == 511) btot[b] = s[511];
}

// exclusive scan of btot[NBUCK] -> bbase[NBUCK+1]
__global__ __launch_bounds__(1024) void bbase_kernel(const int* __restrict__ btot,
                                                     int* __restrict__ bbase) {
  __shared__ int s[1024];
  int v = (threadIdx.x < NBUCK) ? btot[threadIdx.x] : 0;
  s[threadIdx.x] = v;
  __syncthreads();
#pragma unroll
  for (int off = 1; off < 1024; off <<= 1) {
    int t = (threadIdx.x >= off) ? s[threadIdx.x - off] : 0;
    __syncthreads();
    s[threadIdx.x] += t;
    __syncthreads();
  }
  if (threadIdx.x < NBUCK) bbase[threadIdx.x] = s[threadIdx.x] - v;
  if (threadIdx.x == NBUCK - 1) bbase[NBUCK] = s[threadIdx.x];
}

// bucket placement: write packed edge {src | dst_lo<<24, kw2} bucket-sorted
__global__ __launch_bounds__(256) void bplace_kernel(
    const int* __restrict__ src, const int* __restrict__ dst,
    const float* __restrict__ kw, const int* __restrict__ bhT,
    const int* __restrict__ bbase, uint2* __restrict__ bsorted) {
  __shared__ int cur[NBUCK];
  for (int k = threadIdx.x; k < NBUCK; k += 256)
    cur[k] = bbase[k] + bhT[k * NBLK_A + blockIdx.x];
  __syncthreads();
  int base = blockIdx.x * EPB;
  for (int i = threadIdx.x; i < EPB; i += 256) {
    int e = base + i;
    int d = dst[e];
    int p = atomicAdd(&cur[d >> 8], 1);
    uint2 u;
    u.x = (unsigned)src[e] | ((unsigned)(d & 255) << 24);
    u.y = pack2(kw[e], kw[NE + e]);
    bsorted[p] = u;
  }
}

// ======================= stage 2: per-node counts (LDS) =======================

__global__ __launch_bounds__(256) void nhist_kernel(const uint2* __restrict__ bsorted,
                                                    const int* __restrict__ bbase,
                                                    int* __restrict__ cnt) {
  __shared__ int h[256];
  h[threadIdx.x] = 0;
  __syncthreads();
  int b = blockIdx.x;
  int r0 = bbase[b], r1 = bbase[b + 1];
  for (int i = r0 + threadIdx.x; i < r1; i += 256)
    atomicAdd(&h[bsorted[i].x >> 24], 1);
  __syncthreads();
  int node = b * 256 + threadIdx.x;
  if (node < NN) cnt[node] = h[threadIdx.x];
}

// node-level scans (global exclusive offsets)
__global__ __launch_bounds__(256) void scan1_kernel(const int* __restrict__ cnt,
                                                    int* __restrict__ offs,
                                                    int* __restrict__ bsums) {
  __shared__ int s[256];
  int i = blockIdx.x * 256 + threadIdx.x;
  int v = (i < NN) ? cnt[i] : 0;
  s[threadIdx.x] = v;
  __syncthreads();
#pragma unroll
  for (int off = 1; off < 256; off <<= 1) {
    int t = (threadIdx.x >= off) ? s[threadIdx.x - off] : 0;
    __syncthreads();
    s[threadIdx.x] += t;
    __syncthreads();
  }
  if (i < NN) offs[i] = s[threadIdx.x];
  if (threadIdx.x == 255) bsums[blockIdx.x] = s[255];
}

__global__ __launch_bounds__(1024) void scan2_kernel(int* __restrict__ bsums, int nb) {
  __shared__ int s[1024];
  int v = (threadIdx.x < nb) ? bsums[threadIdx.x] : 0;
  s[threadIdx.x] = v;
  __syncthreads();
#pragma unroll
  for (int off = 1; off < 1024; off <<= 1) {
    int t = (threadIdx.x >= off) ? s[threadIdx.x - off] : 0;
    __syncthreads();
    s[threadIdx.x] += t;
    __syncthreads();
  }
  if (threadIdx.x < nb) bsums[threadIdx.x] = s[threadIdx.x] - v;  // exclusive
}

__global__ __launch_bounds__(256) void scan3_kernel(const int* __restrict__ cnt,
                                                    const int* __restrict__ bsums,
                                                    int* __restrict__ offs) {
  int i = blockIdx.x * 256 + threadIdx.x;
  if (i >= NN) return;
  offs[i] = offs[i] - cnt[i] + bsums[blockIdx.x];
}

// final placement within bucket window (L2-resident writes)
__global__ __launch_bounds__(256) void nplace_kernel(const uint2* __restrict__ bsorted,
                                                     const int* __restrict__ bbase,
                                                     const int* __restrict__ offs,
                                                     uint2* __restrict__ sedge) {
  __shared__ int cur[256];
  int b = blockIdx.x;
  int node = b * 256 + threadIdx.x;
  cur[threadIdx.x] = (node < NN) ? offs[node] : 0;
  __syncthreads();
  int r0 = bbase[b], r1 = bbase[b + 1];
  for (int i = r0 + threadIdx.x; i < r1; i += 256) {
    uint2 u = bsorted[i];
    int p = atomicAdd(&cur[u.x >> 24], 1);
    u.x &= 0x00FFFFFFu;  // pure src index
    sedge[p] = u;
  }
}

// ============== fused conv0 + mlp0 + l2norm -> h1 bf16 [N,32] ==============
// 2 lanes per node: lane parity q owns x-chunk float4 at +q*4.

__global__ __launch_bounds__(256) void fused0_kernel(
    const float* __restrict__ x, const int* __restrict__ offs,
    const int* __restrict__ cnt, const uint2* __restrict__ sedge,
    const float* __restrict__ W0, const float* __restrict__ b0,
    unsigned short* __restrict__ h1bf) {
  __shared__ float w0t[32][16];  // w0t[j][k] = W0[k*32+j]
  __shared__ float b0s[32];
  int tid = threadIdx.x;
  for (int i = tid; i < 16 * 32; i += 256) {
    int k = i >> 5, j = i & 31;
    w0t[j][k] = W0[i];
  }
  if (tid < 32) b0s[tid] = b0[tid];
  __syncthreads();

  int idx = blockIdx.x * 256 + tid;
  int node = idx >> 1, q = idx & 1;
  if (node >= NN) return;

  int start = offs[node];
  int deg = cnt[node];
  float a0 = 0.f, a1 = 0.f, a2 = 0.f, a3 = 0.f;  // k0 * own x-chunk
  float c0 = 0.f, c1 = 0.f, c2 = 0.f, c3 = 0.f;  // k1 * own x-chunk

  for (int i = 0; i < deg; ++i) {
    uint2 e = sedge[start + i];
    float k0 = bflo(e.y), k1 = bfhi(e.y);
    float4 v = *reinterpret_cast<const float4*>(x + (size_t)e.x * 8 + q * 4);
    a0 += k0 * v.x; a1 += k0 * v.y; a2 += k0 * v.z; a3 += k0 * v.w;
    c0 += k1 * v.x; c1 += k1 * v.y; c2 += k1 * v.z; c3 += k1 * v.w;
  }

  // exchange with partner lane (lane^1) to assemble full h16
  float pa0 = __shfl_xor(a0, 1), pa1 = __shfl_xor(a1, 1);
  float pa2 = __shfl_xor(a2, 1), pa3 = __shfl_xor(a3, 1);
  float pc0 = __shfl_xor(c0, 1), pc1 = __shfl_xor(c1, 1);
  float pc2 = __shfl_xor(c2, 1), pc3 = __shfl_xor(c3, 1);
  bool q0 = (q == 0);
  // h[k]: k0-part of x[0..7] then k1-part of x[0..7]
  float h0 = q0 ? a0 : pa0, h1 = q0 ? a1 : pa1;
  float h2 = q0 ? a2 : pa2, h3 = q0 ? a3 : pa3;
  float h4 = q0 ? pa0 : a0, h5 = q0 ? pa1 : a1;
  float h6 = q0 ? pa2 : a2, h7 = q0 ? pa3 : a3;
  float h8 = q0 ? c0 : pc0, h9 = q0 ? c1 : pc1;
  float h10 = q0 ? c2 : pc2, h11 = q0 ? c3 : pc3;
  float h12 = q0 ? pc0 : c0, h13 = q0 ? pc1 : c1;
  float h14 = q0 ? pc2 : c2, h15 = q0 ? pc3 : c3;

  // each lane computes 16 of the 32 outputs: j in [q*16, q*16+16)
  float o[16];
  float ss = 0.f;
#pragma unroll
  for (int jj = 0; jj < 16; ++jj) {
    int j = q * 16 + jj;
    float acc = b0s[j];
    acc += h0 * w0t[j][0] + h1 * w0t[j][1] + h2 * w0t[j][2] + h3 * w0t[j][3];
    acc += h4 * w0t[j][4] + h5 * w0t[j][5] + h6 * w0t[j][6] + h7 * w0t[j][7];
    acc += h8 * w0t[j][8] + h9 * w0t[j][9] + h10 * w0t[j][10] + h11 * w0t[j][11];
    acc += h12 * w0t[j][12] + h13 * w0t[j][13] + h14 * w0t[j][14] + h15 * w0t[j][15];
    o[jj] = acc;
    ss += acc * acc;
  }
  ss += __shfl_xor(ss, 1);
  float inv = 1.f / fmaxf(sqrtf(ss), 1e-12f);

  uint4* op = reinterpret_cast<uint4*>(h1bf + (size_t)node * 32 + q * 16);
  uint4 u0, u1;
  u0.x = pack2(o[0] * inv, o[1] * inv);  u0.y = pack2(o[2] * inv, o[3] * inv);
  u0.z = pack2(o[4] * inv, o[5] * inv);  u0.w = pack2(o[6] * inv, o[7] * inv);
  u1.x = pack2(o[8] * inv, o[9] * inv);  u1.y = pack2(o[10] * inv, o[11] * inv);
  u1.z = pack2(o[12] * inv, o[13] * inv); u1.w = pack2(o[14] * inv, o[15] * inv);
  op[0] = u0;
  op[1] = u1;
}

// ============== gather1: CSR gather of h1 -> g bf16 [N,64] ==============
// 4 lanes per node: lane q reads h1 chunk [q*8, q*8+8), writes g chunks
// [q*8,+8) (k0) and [32+q*8,+8) (k1).

__global__ __launch_bounds__(256) void gather1_kernel(
    const unsigned short* __restrict__ h1bf, const int* __restrict__ offs,
    const int* __restrict__ cnt, const uint2* __restrict__ sedge,
    unsigned short* __restrict__ gbf) {
  int idx = blockIdx.x * 256 + threadIdx.x;
  int node = idx >> 2, q = idx & 3;
  if (node >= NN) return;
  int start = offs[node];
  int deg = cnt[node];

  float g0[8], g1[8];
#pragma unroll
  for (int k = 0; k < 8; ++k) { g0[k] = 0.f; g1[k] = 0.f; }

  for (int i = 0; i < deg; ++i) {
    uint2 e = sedge[start + i];
    float k0 = bflo(e.y), k1 = bfhi(e.y);
    uint4 u = *reinterpret_cast<const uint4*>(h1bf + (size_t)e.x * 32 + q * 8);
    float v0 = bflo(u.x), v1 = bfhi(u.x);
    float v2 = bflo(u.y), v3 = bfhi(u.y);
    float v4 = bflo(u.z), v5 = bfhi(u.z);
    float v6 = bflo(u.w), v7 = bfhi(u.w);
    g0[0] += k0 * v0; g0[1] += k0 * v1; g0[2] += k0 * v2; g0[3] += k0 * v3;
    g0[4] += k0 * v4; g0[5] += k0 * v5; g0[6] += k0 * v6; g0[7] += k0 * v7;
    g1[0] += k1 * v0; g1[1] += k1 * v1; g1[2] += k1 * v2; g1[3] += k1 * v3;
    g1[4] += k1 * v4; g1[5] += k1 * v5; g1[6] += k1 * v6; g1[7] += k1 * v7;
  }

  uint4 s0, s1;
  s0.x = pack2(g0[0], g0[1]); s0.y = pack2(g0[2], g0[3]);
  s0.z = pack2(g0[4], g0[5]); s0.w = pack2(g0[6], g0[7]);
  s1.x = pack2(g1[0], g1[1]); s1.y = pack2(g1[2], g1[3]);
  s1.z = pack2(g1[4], g1[5]); s1.w = pack2(g1[6], g1[7]);
  *reinterpret_cast<uint4*>(gbf + (size_t)node * 64 + q * 8) = s0;
  *reinterpret_cast<uint4*>(gbf + (size_t)node * 64 + 32 + q * 8) = s1;
}

// ============== mlp1: MFMA 16x16x32_bf16, 16 nodes per wave-tile ==============
// A: row=lane&15, k=(lane>>4)*8+i ; B: col=lane&15, k=(lane>>4)*8+i
// D: col=lane&15, row=(lane>>4)*4+q   [m89-verified]

__global__ __launch_bounds__(256) void mlp1_kernel(
    const unsigned short* __restrict__ gbf,
    const float* __restrict__ W1, const float* __restrict__ b1,
    const float* __restrict__ W2, const float* __restrict__ b2,
    float* __restrict__ out) {
  __shared__ __align__(16) short hlds[4][16][136];
  int tid = threadIdx.x;
  int wave = tid >> 6, lane = tid & 63;
  int lg = lane >> 4;
  int lr = lane & 15;

  bf16x8 w1f[8][2];
#pragma unroll
  for (int n = 0; n < 8; ++n)
#pragma unroll
    for (int ks = 0; ks < 2; ++ks) {
      bf16x8 f;
#pragma unroll
      for (int i = 0; i < 8; ++i)
        f[i] = (short)f2bfu(W1[(size_t)(ks * 32 + lg * 8 + i) * 128 + n * 16 + lr]);
      w1f[n][ks] = f;
    }
  bf16x8 w2f[4][4];
#pragma unroll
  for (int n2 = 0; n2 < 4; ++n2)
#pragma unroll
    for (int ks = 0; ks < 4; ++ks) {
      bf16x8 f;
#pragma unroll
      for (int i = 0; i < 8; ++i)
        f[i] = (short)f2bfu(W2[(size_t)(ks * 32 + lg * 8 + i) * 64 + n2 * 16 + lr]);
      w2f[n2][ks] = f;
    }
  float b1v[8], b2v[4];
#pragma unroll
  for (int n = 0; n < 8; ++n) b1v[n] = b1[n * 16 + lr];
#pragma unroll
  for (int n2 = 0; n2 < 4; ++n2) b2v[n2] = b2[n2 * 16 + lr];

  for (int tile = blockIdx.x * 4 + wave; tile < NT_MLP1; tile += gridDim.x * 4) {
    int base = tile * 16;
    const bf16x8* grow = reinterpret_cast<const bf16x8*>(gbf + (size_t)(base + lr) * 64);
    bf16x8 a1_0 = grow[lg];
    bf16x8 a1_1 = grow[4 + lg];

#pragma unroll
    for (int n = 0; n < 8; ++n) {
      f32x4 acc = {0.f, 0.f, 0.f, 0.f};
      acc = __builtin_amdgcn_mfma_f32_16x16x32_bf16(a1_0, w1f[n][0], acc, 0, 0, 0);
      acc = __builtin_amdgcn_mfma_f32_16x16x32_bf16(a1_1, w1f[n][1], acc, 0, 0, 0);
#pragma unroll
      for (int q = 0; q < 4; ++q) {
        float v = fmaxf(acc[q] + b1v[n], 0.f);
        hlds[wave][lg * 4 + q][n * 16 + lr] = (short)f2bfu(v);
      }
    }

    bf16x8 a2[4];
#pragma unroll
    for (int ks = 0; ks < 4; ++ks)
      a2[ks] = *reinterpret_cast<const bf16x8*>(&hlds[wave][lr][ks * 32 + lg * 8]);
    f32x4 acc2[4];
#pragma unroll
    for (int n2 = 0; n2 < 4; ++n2) {
      f32x4 a = {0.f, 0.f, 0.f, 0.f};
#pragma unroll
      for (int ks = 0; ks < 4; ++ks)
        a = __builtin_amdgcn_mfma_f32_16x16x32_bf16(a2[ks], w2f[n2][ks], a, 0, 0, 0);
      acc2[n2] = a;
    }

#pragma unroll
    for (int q = 0; q < 4; ++q) {
      float s = 0.f;
#pragma unroll
      for (int n2 = 0; n2 < 4; ++n2) {
        float v = acc2[n2][q] + b2v[n2];
        s += v * v;
      }
      s += __shfl_xor(s, 1); s += __shfl_xor(s, 2);
      s += __shfl_xor(s, 4); s += __shfl_xor(s, 8);
      float inv = 1.f / fmaxf(sqrtf(s), 1e-12f);
      size_t rowoff = (size_t)(base + lg * 4 + q) * 64 + lr;
#pragma unroll
      for (int n2 = 0; n2 < 4; ++n2)
        out[rowoff + n2 * 16] = (acc2[n2][q] + b2v[n2]) * inv;
    }
  }
}

// ======================= launch =======================

extern "C" void kernel_launch(void* const* d_in, const int* in_sizes, int n_in,
                              void* d_out, int out_size, void* d_ws, size_t ws_size,
                              hipStream_t stream) {
  const float* x  = (const float*)d_in[0];
  const int* ei   = (const int*)d_in[1];
  const float* kw = (const float*)d_in[2];
  const float* W0 = (const float*)d_in[3];
  const float* b0 = (const float*)d_in[4];
  const float* W1 = (const float*)d_in[5];
  const float* b1 = (const float*)d_in[6];
  const float* W2 = (const float*)d_in[7];
  const float* b2 = (const float*)d_in[8];
  float* out = (float*)d_out;

  const int* src = ei;
  const int* dst = ei + NE;

  // ws layout (8B-aligned chunks), ~67 MB total:
  char* p = (char*)d_ws;
  uint2* bsorted = (uint2*)p;              p += (size_t)NE * 8;          // 25.6 MB
  uint2* sedge   = (uint2*)p;              p += (size_t)NE * 8;          // 25.6 MB
  unsigned short* h1bf = (unsigned short*)p; p += (size_t)NN * 32 * 2;   // 12.8 MB
  int* bhT   = (int*)p;                    p += (size_t)NBUCK * NBLK_A * 4;  // 1.6 MB
  int* btot  = (int*)p;                    p += (size_t)NBUCK * 4;
  int* bbase = (int*)p;                    p += (size_t)(NBUCK + 1) * 4;
  int* cnt   = (int*)p;                    p += (size_t)NN * 4;          // 0.8 MB
  int* offs  = (int*)p;                    p += (size_t)NN * 4;          // 0.8 MB
  int* bsums = (int*)p;                    p += 1024 * 4;
  // gbf reuses bsorted (dead after nplace); NN*64*2 == NE*8 bytes exactly.
  unsigned short* gbf = (unsigned short*)bsorted;

  bhist_kernel<<<NBLK_A, 256, 0, stream>>>(dst, bhT);
  bscan_kernel<<<NBUCK, 512, 0, stream>>>(bhT, btot);
  bbase_kernel<<<1, 1024, 0, stream>>>(btot, bbase);
  bplace_kernel<<<NBLK_A, 256, 0, stream>>>(src, dst, kw, bhT, bbase, bsorted);

  nhist_kernel<<<NBUCK, 256, 0, stream>>>(bsorted, bbase, cnt);
  scan1_kernel<<<NB_SCAN, 256, 0, stream>>>(cnt, offs, bsums);
  scan2_kernel<<<1, 1024, 0, stream>>>(bsums, NB_SCAN);
  scan3_kernel<<<NB_SCAN, 256, 0, stream>>>(cnt, bsums, offs);
  nplace_kernel<<<NBUCK, 256, 0, stream>>>(bsorted, bbase, offs, sedge);

  fused0_kernel<<<(2 * NN + 255) / 256, 256, 0, stream>>>(x, offs, cnt, sedge,
                                                          W0, b0, h1bf);
  gather1_kernel<<<(4 * NN + 255) / 256, 256, 0, stream>>>(h1bf, offs, cnt,
                                                           sedge, gbf);
  mlp1_kernel<<<768, 256, 0, stream>>>(gbf, W1, b1, W2, b2, out);
}